// Round 1
// baseline (1970.558 us; speedup 1.0000x reference)
//
#include <hip/hip_runtime.h>

// LSTM: B=4096, T=512, D=H=25, 3 layers, + MLP head (16 -> 14) + softmax.
// Strategy: one wave (64 lanes) per batch element. Lane l owns gate rows l and
// 64+l (100 rows total, 4*H=100). All weights live in VGPRs (100 regs/lane).
// x_t and h_{t-1} are rebroadcast through a tiny per-wave LDS slot using
// same-address ds_read_b128 broadcasts. No __syncthreads anywhere.
// Inter-layer hidden sequences go through ws (needs 4096*512*25*4 = 210 MB),
// read/written in place by the same wave (safe: program order + write-through L1).

#define NBATCH 4096
#define NT     512
#define ND     25
#define NG     100   // 4*H
#define NL     3

__device__ __forceinline__ float sigf(float x) {
    // sigmoid(x) = 1/(1+e^-x); rcp is ~1ulp, fine vs 2e-3 threshold.
    return __builtin_amdgcn_rcpf(1.0f + __expf(-x));
}

__global__ __launch_bounds__(256)
void lstm_fused(const float* __restrict__ xin,
                const float* __restrict__ Wih,
                const float* __restrict__ Whh,
                const float* __restrict__ bih,
                const float* __restrict__ bhh,
                const float* __restrict__ W1,
                const float* __restrict__ b1,
                const float* __restrict__ W2,
                const float* __restrict__ b2,
                float* __restrict__ out,
                float* __restrict__ ws)
{
    __shared__ __align__(16) float xs[4][32];
    __shared__ __align__(16) float hs[4][32];

    const int wid  = threadIdx.x >> 6;
    const int lane = threadIdx.x & 63;
    const int b    = (blockIdx.x << 2) + wid;   // grid = 1024 blocks -> b in [0,4096)

    const int row0 = lane;                       // rows 0..63
    int row1 = 64 + lane; if (row1 > 99) row1 = 99;  // clamp; lanes>=36 unused

    float wih0[25], whh0[25], wih1[25], whh1[25];

    // zero the LDS slots once (incl. pad lanes)
    if (lane < 32) { xs[wid][lane] = 0.f; hs[wid][lane] = 0.f; }

    for (int l = 0; l < NL; ++l) {
        // ---- load this layer's weights into registers ----
        const float* wihp0 = Wih + (l*NG + row0)*ND;
        const float* whhp0 = Whh + (l*NG + row0)*ND;
        const float* wihp1 = Wih + (l*NG + row1)*ND;
        const float* whhp1 = Whh + (l*NG + row1)*ND;
#pragma unroll
        for (int d = 0; d < 25; ++d) {
            wih0[d] = wihp0[d]; whh0[d] = whhp0[d];
            wih1[d] = wihp1[d]; whh1[d] = whhp1[d];
        }
        const float bias0 = bih[l*NG + row0] + bhh[l*NG + row0];
        const float bias1 = bih[l*NG + row1] + bhh[l*NG + row1];

        // ---- reset recurrent state ----
        float c = 0.f;
        if (lane < 32) hs[wid][lane] = 0.f;

        const float* src = (l == 0) ? (xin + (size_t)b * NT * ND)
                                    : (ws  + (size_t)b * NT * ND);
        float* wsrow = ws + (size_t)b * NT * ND;

        float xv_next = (lane < 25) ? src[lane] : 0.f;   // prefetch t=0

        for (int t = 0; t < NT; ++t) {
            // stage x_t, prefetch x_{t+1}
            if (lane < 25) {
                xs[wid][lane] = xv_next;
                if (t + 1 < NT) xv_next = src[(t + 1) * ND + lane];
            }

            float acc0 = bias0, acc1 = bias1;
#pragma unroll
            for (int c4 = 0; c4 < 7; ++c4) {
                const float4 xv = *(const float4*)&xs[wid][c4 * 4];
                const float4 hv = *(const float4*)&hs[wid][c4 * 4];
                const float xa[4] = {xv.x, xv.y, xv.z, xv.w};
                const float ha[4] = {hv.x, hv.y, hv.z, hv.w};
#pragma unroll
                for (int j = 0; j < 4; ++j) {
                    const int d = c4 * 4 + j;
                    if (d < 25) {
                        acc0 = fmaf(wih0[d], xa[j], acc0);
                        acc1 = fmaf(wih1[d], xa[j], acc1);
                        acc0 = fmaf(whh0[d], ha[j], acc0);
                        acc1 = fmaf(whh1[d], ha[j], acc1);
                    }
                }
            }

            // activations: act0 rows 0..49 sigmoid, 50..63 tanh
            //              act1 rows 64..74 tanh, 75..99 sigmoid
            const float in0 = (lane < 50) ? acc0 : acc0 + acc0;
            const float s0  = sigf(in0);
            const float act0 = (lane < 50) ? s0 : s0 + s0 - 1.0f;
            const float in1 = (lane < 11) ? acc1 + acc1 : acc1;
            const float s1  = sigf(in1);
            const float act1 = (lane < 11) ? s1 + s1 - 1.0f : s1;

            // gather gates for col = lane (meaningful for lane < 25)
            // i: row col       -> act0 own lane
            // f: row 25+col    -> act0 lane 25+col
            // g: row 50+col    -> act0 lane 50+col (col<=13) / act1 lane col-14
            // o: row 75+col    -> act1 lane 11+col
            const float fg = __shfl(act0, (lane + 25) & 63);
            const float ga = __shfl(act0, (lane + 50) & 63);
            const float gb = __shfl(act1, (lane + 50) & 63);  // (col-14)&63 == (col+50)&63
            const float og = __shfl(act1, (lane + 11) & 63);
            const float gg = (lane < 14) ? ga : gb;
            const float ig = act0;

            // cell update (all lanes compute; only lanes<25 meaningful)
            c = fmaf(fg, c, ig * gg);
            float th = sigf(c + c); th = th + th - 1.0f;   // tanh(c)
            const float hnew = og * th;

            if (lane < 25) {
                hs[wid][lane] = hnew;
                if (l < 2) wsrow[t * ND + lane] = hnew;    // feed next layer
            }
        } // t
    } // l

    // ---- head: relu(h @ W1^T + b1) @ W2^T + b2, softmax over 14 ----
    if (lane < 16) {
        float u = b1[lane];
#pragma unroll
        for (int d = 0; d < 25; ++d) u = fmaf(W1[lane * 25 + d], hs[wid][d], u);
        xs[wid][lane] = fmaxf(u, 0.f);
    }
    if (lane < 14) {
        float lg = b2[lane];
#pragma unroll
        for (int r = 0; r < 16; ++r) lg = fmaf(W2[lane * 16 + r], xs[wid][r], lg);
        hs[wid][lane] = lg;
    }
    if (lane < 14) {
        float m = -1e30f;
#pragma unroll
        for (int j = 0; j < 14; ++j) m = fmaxf(m, hs[wid][j]);
        float sum = 0.f;
#pragma unroll
        for (int j = 0; j < 14; ++j) sum += __expf(hs[wid][j] - m);
        const float lg = hs[wid][lane];
        out[b * 14 + lane] = __expf(lg - m) / sum;
    }
}

extern "C" void kernel_launch(void* const* d_in, const int* in_sizes, int n_in,
                              void* d_out, int out_size, void* d_ws, size_t ws_size,
                              hipStream_t stream)
{
    const float* x   = (const float*)d_in[0];
    const float* Wih = (const float*)d_in[1];
    const float* Whh = (const float*)d_in[2];
    const float* bih = (const float*)d_in[3];
    const float* bhh = (const float*)d_in[4];
    const float* W1  = (const float*)d_in[5];
    const float* b1  = (const float*)d_in[6];
    const float* W2  = (const float*)d_in[7];
    const float* b2  = (const float*)d_in[8];
    float* outp = (float*)d_out;
    float* ws   = (float*)d_ws;   // needs 4096*512*25*4 = 209,715,200 bytes

    dim3 grid(NBATCH / 4), block(256);
    hipLaunchKernelGGL(lstm_fused, grid, block, 0, stream,
                       x, Wih, Whh, bih, bhh, W1, b1, W2, b2, outp, ws);
}

// Round 2
// 1883.945 us; speedup vs baseline: 1.0460x; 1.0460x over previous
//
#include <hip/hip_runtime.h>

// LSTM B=4096, T=512, D=H=25, 3 layers + MLP head + softmax.
// R2: two waves per batch element to keep per-lane weights at 52 floats
// (w[0..24]=Wih row, w[25..49]=Whh row) so everything stays in arch VGPRs
// (R1's one-wave-per-batch needed 100 weight floats -> compiler demoted them
// to AGPRs and burned ~300 extra VALU cyc/timestep on v_accvgpr_read).
//
// Wave A (role 0): gate rows 0..49  (i rows 0-24, f rows 25-49) - all sigmoid.
// Wave B (role 1): gate rows 50..99 (g rows 50-74 tanh, o rows 75-99 sigmoid).
// Lane l (<50) owns one gate row. x_t and h_{t-1} live packed in LDS xh[52]
// so the dot product is 13 broadcast ds_read_b128 + 52 FMAs per lane.
// Wave A lanes 0-24 own c and the h update. 2 barriers per timestep.

#define NBATCH 4096
#define NT     512
#define ND     25
#define NG     100
#define NL     3

__device__ __forceinline__ float sigf(float x) {
    return __builtin_amdgcn_rcpf(1.0f + __expf(-x));
}
__device__ __forceinline__ float tanhfast(float x) {
    float s = sigf(x + x);
    return s + s - 1.0f;
}

__global__ __launch_bounds__(256, 4)
void lstm2(const float* __restrict__ xin,
           const float* __restrict__ Wih,
           const float* __restrict__ Whh,
           const float* __restrict__ bih,
           const float* __restrict__ bhh,
           const float* __restrict__ W1,
           const float* __restrict__ b1,
           const float* __restrict__ W2,
           const float* __restrict__ b2,
           float* __restrict__ out,
           float* __restrict__ ws)
{
    // per block: 2 batches. xh = [x_t(25) | h_{t-1}(25) | pad(6, zero)]
    __shared__ __align__(16) float xh[2][56];
    __shared__ float act[2][112];   // [0..49] = wave A acts, [56..105] = wave B acts

    const int wid  = threadIdx.x >> 6;
    const int lane = threadIdx.x & 63;
    const int wb   = wid >> 1;          // batch slot in block (0/1)
    const int role = wid & 1;           // 0 = A (i,f + updater), 1 = B (g,o)
    const int b    = (blockIdx.x << 1) + wb;

    const int  lrow    = (lane < 50) ? lane : 49;   // clamp; lanes 50-63 compute garbage, never stored
    const bool updater = (role == 0) && (lane < 25);

    float w[52];
    w[50] = 0.f; w[51] = 0.f;   // pad so the 13th float4 chunk contributes 0

    for (int l = 0; l < NL; ++l) {
        // ---- weights for this wave's row into VGPRs ----
        const int row = l * NG + role * 50 + lrow;
        const float* wihp = Wih + row * ND;
        const float* whhp = Whh + row * ND;
#pragma unroll
        for (int d = 0; d < 25; ++d) { w[d] = wihp[d]; w[25 + d] = whhp[d]; }
        const float bias = bih[row] + bhh[row];

        const float* src = (l == 0) ? (xin + (size_t)b * NT * ND)
                                    : (ws  + (size_t)b * NT * ND);
        float* wsrow = ws + (size_t)b * NT * ND;

        float c = 0.f;
        float xv_next = 0.f;
        if (updater) {
            xh[wb][lane] = src[lane];                 // x_0
            xv_next = src[ND + lane];                 // x_1 (NT >= 2)
        }
        if (role == 0 && lane < 31) xh[wb][25 + lane] = 0.f;  // h=0 + zero pads
        __syncthreads();

        for (int t = 0; t < NT; ++t) {
            // ---- gate dot product: 13 broadcast b128 reads + 52 FMAs ----
            float acc = bias;
#pragma unroll
            for (int c4 = 0; c4 < 13; ++c4) {
                const float4 v = *(const float4*)&xh[wb][c4 * 4];
                acc = fmaf(w[c4 * 4 + 0], v.x, acc);
                acc = fmaf(w[c4 * 4 + 1], v.y, acc);
                acc = fmaf(w[c4 * 4 + 2], v.z, acc);
                acc = fmaf(w[c4 * 4 + 3], v.w, acc);
            }
            // ---- activation ----
            float a;
            if (role == 0) a = sigf(acc);                          // i, f
            else           a = (lane < 25) ? tanhfast(acc)          // g
                                           : sigf(acc);             // o
            if (lane < 50) act[wb][role * 56 + lane] = a;
            __syncthreads();   // acts visible; also: everyone done reading xh

            // ---- cell/hidden update (wave A lanes 0-24) ----
            if (updater) {
                const float ig = act[wb][lane];
                const float fg = act[wb][25 + lane];
                const float gg = act[wb][56 + lane];
                const float og = act[wb][81 + lane];
                c = fmaf(fg, c, ig * gg);
                const float h = og * tanhfast(c);
                xh[wb][25 + lane] = h;            // h_t for next step
                xh[wb][lane]      = xv_next;      // x_{t+1}
                if (l < 2) wsrow[t * ND + lane] = h;
                if (t + 2 < NT) xv_next = src[(t + 2) * ND + lane];
            }
            __syncthreads();   // xh (h_t, x_{t+1}) visible
        }
    }

    // ---- head: relu(h W1^T + b1) W2^T + b2, softmax(14). Wave A only. ----
    if (role == 0 && lane < 16) {
        float u = b1[lane];
#pragma unroll
        for (int d = 0; d < 25; ++d) u = fmaf(W1[lane * 25 + d], xh[wb][25 + d], u);
        act[wb][lane] = fmaxf(u, 0.f);
    }
    if (role == 0 && lane < 14) {
        float lg = b2[lane];
#pragma unroll
        for (int r = 0; r < 16; ++r) lg = fmaf(W2[lane * 16 + r], act[wb][r], lg);
        act[wb][32 + lane] = lg;
    }
    if (role == 0 && lane < 14) {
        float m = -1e30f;
#pragma unroll
        for (int j = 0; j < 14; ++j) m = fmaxf(m, act[wb][32 + j]);
        float sum = 0.f;
#pragma unroll
        for (int j = 0; j < 14; ++j) sum += __expf(act[wb][32 + j] - m);
        out[b * 14 + lane] = __expf(act[wb][32 + lane] - m) / sum;
    }
}

extern "C" void kernel_launch(void* const* d_in, const int* in_sizes, int n_in,
                              void* d_out, int out_size, void* d_ws, size_t ws_size,
                              hipStream_t stream)
{
    const float* x   = (const float*)d_in[0];
    const float* Wih = (const float*)d_in[1];
    const float* Whh = (const float*)d_in[2];
    const float* bih = (const float*)d_in[3];
    const float* bhh = (const float*)d_in[4];
    const float* W1  = (const float*)d_in[5];
    const float* b1  = (const float*)d_in[6];
    const float* W2  = (const float*)d_in[7];
    const float* b2  = (const float*)d_in[8];
    float* outp = (float*)d_out;
    float* ws   = (float*)d_ws;   // 4096*512*25*4 = 209,715,200 bytes

    dim3 grid(NBATCH / 2), block(256);
    hipLaunchKernelGGL(lstm2, grid, block, 0, stream,
                       x, Wih, Whh, bih, bhh, W1, b1, W2, b2, outp, ws);
}